// Round 3
// baseline (2332.331 us; speedup 1.0000x reference)
//
#include <hip/hip_runtime.h>
#include <math.h>

#define BATCH 32
#define TLEN 8192
#define NCH 128          // chunks
#define CLEN 64          // steps per chunk
#define SUBL 8           // steps per sub-chunk
#define NSUB 8           // sub-chunks per chunk
#define NROWS (BATCH*TLEN)   // 262144 rows

// ---------------------------------------------------------------------------
// HiPPO step: s <- (I - A/t) s + (x/t) * r
// (A s)[n] = (n+1)*s[n] + r[n] * sum_{m<n} r[m]*s[m]
// ---------------------------------------------------------------------------
__device__ __forceinline__ void hippo_step(float s[8], float inv_t, float xb) {
    const float R[8] = {1.0f, 1.7320508075688772f, 2.23606797749979f,
                        2.6457513110645907f, 3.0f, 3.3166247903554f,
                        3.605551275463989f, 3.872983346207417f};
    float p = 0.0f;
    #pragma unroll
    for (int n = 0; n < 8; n++) {
        float sn = s[n];
        float as = fmaf(R[n], p, (float)(n + 1) * sn);
        s[n] = fmaf(-inv_t, as, fmaf(xb, R[n], sn));
        p = fmaf(R[n], sn, p);
    }
}

// ---------------------------------------------------------------------------
// Kernel A: per-chunk runs. Threads 64..71 run unit-vector starts (P columns),
// threads 0..63 run zero starts with input (V). Every SUBL steps the running
// state is dumped -> sub-chunk transition data for the fine expand.
// ---------------------------------------------------------------------------
__global__ void hippo_chunk_kernel(const float* __restrict__ x_seq,
                                   float* __restrict__ Psub,  // [NCH][NSUB][8][8]
                                   float* __restrict__ Vsub,  // [NCH][NSUB][64][8]
                                   float* __restrict__ Pfin,  // [NCH][8][8]
                                   float* __restrict__ Vfin)  // [NCH][64][8]
{
    int chunk = blockIdx.x;
    int tid = threadIdx.x;
    if (tid >= 72) return;
    bool isP = tid >= 64;
    int col = tid - 64;
    int b = tid >> 1, c = tid & 1;

    float s[8];
    #pragma unroll
    for (int n = 0; n < 8; n++) s[n] = (isP && n == col) ? 1.0f : 0.0f;

    int t0 = chunk * CLEN;
    for (int i = 0; i < CLEN; i++) {
        if ((i & (SUBL - 1)) == 0) {
            int sub = i >> 3;
            if (isP) {
                #pragma unroll
                for (int n = 0; n < 8; n++)
                    Psub[(((size_t)chunk * NSUB + sub) * 8 + n) * 8 + col] = s[n];
            } else {
                #pragma unroll
                for (int n = 0; n < 8; n++)
                    Vsub[(((size_t)chunk * NSUB + sub) * 64 + tid) * 8 + n] = s[n];
            }
        }
        float tf = (float)(t0 + i + 1);
        float inv_t = 1.0f / tf;
        float x = 0.0f;
        if (!isP) x = x_seq[((size_t)(b * TLEN + t0 + i)) * 2 + c];
        hippo_step(s, inv_t, x * inv_t);
    }
    if (isP) {
        #pragma unroll
        for (int n = 0; n < 8; n++) Pfin[((size_t)chunk * 8 + n) * 8 + col] = s[n];
    } else {
        #pragma unroll
        for (int n = 0; n < 8; n++) Vfin[((size_t)chunk * 64 + tid) * 8 + n] = s[n];
    }
}

// ---------------------------------------------------------------------------
// Kernel B: sequential composition across chunks. One thread per (b,c).
// ---------------------------------------------------------------------------
__global__ void hippo_compose_kernel(const float* __restrict__ Pfin,
                                     const float* __restrict__ Vfin,
                                     float* __restrict__ S0)   // [NCH][64][8]
{
    int tid = threadIdx.x;   // 0..63
    float s[8];
    #pragma unroll
    for (int n = 0; n < 8; n++) s[n] = 0.0f;

    #pragma unroll 2
    for (int chunk = 0; chunk < NCH; chunk++) {
        #pragma unroll
        for (int n = 0; n < 8; n++) S0[((size_t)chunk * 64 + tid) * 8 + n] = s[n];
        float ns[8];
        #pragma unroll
        for (int n = 0; n < 8; n++) {
            float acc = Vfin[((size_t)chunk * 64 + tid) * 8 + n];
            #pragma unroll
            for (int m = 0; m < 8; m++)
                acc = fmaf(Pfin[((size_t)chunk * 8 + n) * 8 + m], s[m], acc);
            ns[n] = acc;
        }
        #pragma unroll
        for (int n = 0; n < 8; n++) s[n] = ns[n];
    }
}

// ---------------------------------------------------------------------------
// Kernel C: fine expand. One thread per (b, chunk, sub, c).
// ---------------------------------------------------------------------------
__global__ __launch_bounds__(256) void hippo_expand_kernel(
    const float* __restrict__ x_seq,
    const float* __restrict__ Psub,
    const float* __restrict__ Vsub,
    const float* __restrict__ S0,
    float* __restrict__ h)               // [NROWS][16]
{
    int gid = blockIdx.x * 256 + threadIdx.x;   // 65536
    int c = gid & 1;
    int b = (gid >> 1) & 31;
    int sub = (gid >> 6) & 7;
    int chunk = gid >> 9;
    int seq = b * 2 + c;

    float s0v[8];
    #pragma unroll
    for (int n = 0; n < 8; n++)
        s0v[n] = S0[((size_t)chunk * 64 + seq) * 8 + n];

    const float* Pp = &Psub[((size_t)chunk * NSUB + sub) * 64];
    const float* Vp = &Vsub[(((size_t)chunk * NSUB + sub) * 64 + seq) * 8];

    float s[8];
    #pragma unroll
    for (int n = 0; n < 8; n++) {
        float acc = Vp[n];
        #pragma unroll
        for (int m = 0; m < 8; m++)
            acc = fmaf(Pp[n * 8 + m], s0v[m], acc);
        s[n] = acc;
    }

    int t0 = chunk * CLEN + sub * SUBL;
    #pragma unroll
    for (int i = 0; i < SUBL; i++) {
        int t = t0 + i;
        float tf = (float)(t + 1);
        float inv_t = 1.0f / tf;
        float x = x_seq[((size_t)(b * TLEN + t)) * 2 + c];
        hippo_step(s, inv_t, x * inv_t);
        float4* hp = (float4*)&h[((size_t)(b * TLEN + t)) * 16 + c * 8];
        hp[0] = make_float4(s[0], s[1], s[2], s[3]);
        hp[1] = make_float4(s[4], s[5], s[6], s[7]);
    }
}

// ---------------------------------------------------------------------------
// KAN: 4-nonzero-basis closed form for uniform cubic B-spline.
// ---------------------------------------------------------------------------
__device__ __forceinline__ void bspline4(float x, float& B0, float& B1,
                                         float& B2, float& B3, int& m)
{
    float tt = fmaf(x, 5.0f, 8.0f);        // (x + 1.6) * 5
    float fm = floorf(tt);
    float u = tt - fm;
    bool valid = (fm >= 0.0f) && (fm <= 15.0f);
    float u2 = u * u, u3 = u2 * u;
    float um = 1.0f - u;
    B0 = um * um * um * (1.0f / 6.0f);
    B3 = u3 * (1.0f / 6.0f);
    B1 = fmaf(3.0f, u3, fmaf(-6.0f, u2, 4.0f)) * (1.0f / 6.0f);
    B2 = fmaf(-3.0f, u3, fmaf(3.0f, u2, fmaf(3.0f, u, 1.0f))) * (1.0f / 6.0f);
    float msk = valid ? 1.0f : 0.0f;
    B0 *= msk; B1 *= msk; B2 *= msk; B3 *= msk;
    m = valid ? (int)fm : 0;
}

__device__ __forceinline__ float silu(float x) {
    return x / (1.0f + __expf(-x));
}

// All three layers fused; activations live in registers. NO min-waves
// launch-bounds arg: round-2's (256,4) capped VGPR at 64 and demoted the
// activation arrays to scratch (2.3 GB spill writes, 9x regression).
__global__ __launch_bounds__(256) void kan_kernel(
    const float* __restrict__ h,         // [NROWS][16]
    const float* __restrict__ wb1, const float* __restrict__ ws1,
    const float* __restrict__ wb2, const float* __restrict__ ws2,
    const float* __restrict__ wb3, const float* __restrict__ ws3,
    float* __restrict__ out)
{
    // phase1: ws1p[32][304] @0, wb1[512] @9728           (10240 used)
    // phase2: ws2p[16][608] @0, ws3p[304] @9728, wb2[512] @10032, wb3[16] @10544
    __shared__ float wlds[10560];
    int tid = threadIdx.x;
    int row = blockIdx.x * 256 + tid;

    // preload this row's 16 inputs; vmcnt drains under the LDS staging work
    float x[16];
    {
        const float4* hp = (const float4*)(h + (size_t)row * 16);
        float4 a0 = hp[0], a1 = hp[1], a2 = hp[2], a3 = hp[3];
        x[0]=a0.x; x[1]=a0.y; x[2]=a0.z; x[3]=a0.w;
        x[4]=a1.x; x[5]=a1.y; x[6]=a1.z; x[7]=a1.w;
        x[8]=a2.x; x[9]=a2.y; x[10]=a2.z; x[11]=a2.w;
        x[12]=a3.x; x[13]=a3.y; x[14]=a3.z; x[15]=a3.w;
    }

    // ---- stage ws1 padded + wb1
    for (int idx = tid; idx < 10240; idx += 256) {
        float v = 0.0f;
        if (idx < 9728) {
            int o = idx / 304;
            int k = idx - o * 304;
            int ii = k / 19;
            int jj = k - ii * 19 - 3;
            if (jj >= 0 && jj < 13) v = ws1[o * 208 + ii * 13 + jj];
        } else {
            v = wb1[idx - 9728];
        }
        wlds[idx] = v;
    }
    __syncthreads();

    // ---- layer 1: 16 -> 32
    float acc1[32];
    #pragma unroll
    for (int o = 0; o < 32; o++) acc1[o] = 0.0f;

    #pragma unroll
    for (int i = 0; i < 16; i++) {
        float xv = x[i];
        float sx = silu(xv);
        float B0, B1, B2, B3; int m;
        bspline4(xv, B0, B1, B2, B3, m);
        const float* wp = &wlds[i * 19 + m];
        const float* wbp = &wlds[9728 + i];
        #pragma unroll
        for (int o = 0; o < 32; o++) {
            float a = acc1[o];
            a = fmaf(sx, wbp[o * 16], a);
            const float* w = wp + o * 304;
            a = fmaf(B0, w[0], a);
            a = fmaf(B1, w[1], a);
            a = fmaf(B2, w[2], a);
            a = fmaf(B3, w[3], a);
            acc1[o] = a;
        }
    }
    __syncthreads();   // done reading phase-1 weights

    // ---- stage ws2 + ws3 + wb2 + wb3
    for (int idx = tid; idx < 10560; idx += 256) {
        float v = 0.0f;
        if (idx < 9728) {
            int o = idx / 608;
            int k = idx - o * 608;
            int ii = k / 19;
            int jj = k - ii * 19 - 3;
            if (jj >= 0 && jj < 13) v = ws2[o * 416 + ii * 13 + jj];
        } else if (idx < 10032) {
            int k = idx - 9728;
            int ii = k / 19;
            int jj = k - ii * 19 - 3;
            if (jj >= 0 && jj < 13) v = ws3[ii * 13 + jj];
        } else if (idx < 10544) {
            v = wb2[idx - 10032];
        } else {
            v = wb3[idx - 10544];
        }
        wlds[idx] = v;
    }
    __syncthreads();

    // ---- layer 2: 32 -> 16 (input = acc1 in registers)
    float acc2[16];
    #pragma unroll
    for (int o = 0; o < 16; o++) acc2[o] = 0.0f;

    #pragma unroll
    for (int i = 0; i < 32; i++) {
        float xv = acc1[i];
        float sx = silu(xv);
        float B0, B1, B2, B3; int m;
        bspline4(xv, B0, B1, B2, B3, m);
        const float* wp = &wlds[i * 19 + m];
        const float* wbp = &wlds[10032 + i];
        #pragma unroll
        for (int o = 0; o < 16; o++) {
            float a = acc2[o];
            a = fmaf(sx, wbp[o * 32], a);
            const float* w = wp + o * 608;
            a = fmaf(B0, w[0], a);
            a = fmaf(B1, w[1], a);
            a = fmaf(B2, w[2], a);
            a = fmaf(B3, w[3], a);
            acc2[o] = a;
        }
    }

    // ---- layer 3: 16 -> 1 (input = acc2 in registers)
    float acc3 = 0.0f;
    #pragma unroll
    for (int i = 0; i < 16; i++) {
        float xv = acc2[i];
        float sx = silu(xv);
        float B0, B1, B2, B3; int m;
        bspline4(xv, B0, B1, B2, B3, m);
        const float* wp = &wlds[9728 + i * 19 + m];
        float a = acc3;
        a = fmaf(sx, wlds[10544 + i], a);
        a = fmaf(B0, wp[0], a);
        a = fmaf(B1, wp[1], a);
        a = fmaf(B2, wp[2], a);
        a = fmaf(B3, wp[3], a);
        acc3 = a;
    }
    out[row] = acc3;
}

// ---------------------------------------------------------------------------
extern "C" void kernel_launch(void* const* d_in, const int* in_sizes, int n_in,
                              void* d_out, int out_size, void* d_ws, size_t ws_size,
                              hipStream_t stream) {
    const float* x_seq = (const float*)d_in[0];
    const float* wb1   = (const float*)d_in[1];
    const float* ws1   = (const float*)d_in[2];
    const float* wb2   = (const float*)d_in[3];
    const float* ws2   = (const float*)d_in[4];
    const float* wb3   = (const float*)d_in[5];
    const float* ws3   = (const float*)d_in[6];

    float* ws   = (float*)d_ws;
    float* Psub = ws;                   // 128*8*64        =   65536
    float* Vsub = ws + 65536;           // 128*8*64*8      =  524288
    float* Pfin = ws + 589824;          // 128*64          =    8192
    float* Vfin = ws + 598016;          // 128*64*8        =   65536
    float* S0   = ws + 663552;          // 128*64*8        =   65536
    float* h    = ws + 729088;          // 262144*16       = 4194304
    float* out  = (float*)d_out;

    hipLaunchKernelGGL(hippo_chunk_kernel,   dim3(NCH), dim3(128), 0, stream,
                       x_seq, Psub, Vsub, Pfin, Vfin);
    hipLaunchKernelGGL(hippo_compose_kernel, dim3(1),   dim3(64),  0, stream,
                       Pfin, Vfin, S0);
    hipLaunchKernelGGL(hippo_expand_kernel,  dim3(256), dim3(256), 0, stream,
                       x_seq, Psub, Vsub, S0, h);
    hipLaunchKernelGGL(kan_kernel, dim3(NROWS / 256), dim3(256), 0, stream,
                       h, wb1, ws1, wb2, ws2, wb3, ws3, out);
}

// Round 4
// 220.862 us; speedup vs baseline: 10.5601x; 10.5601x over previous
//
#include <hip/hip_runtime.h>
#include <math.h>

#define BATCH 32
#define TLEN 8192
#define NCH 128          // chunks
#define CLEN 64          // steps per chunk
#define SUBL 8           // steps per sub-chunk
#define NSUB 8           // sub-chunks per chunk
#define NROWS (BATCH*TLEN)   // 262144 rows

// ---------------------------------------------------------------------------
// HiPPO step: s <- (I - A/t) s + (x/t) * r
// ---------------------------------------------------------------------------
__device__ __forceinline__ void hippo_step(float s[8], float inv_t, float xb) {
    const float R[8] = {1.0f, 1.7320508075688772f, 2.23606797749979f,
                        2.6457513110645907f, 3.0f, 3.3166247903554f,
                        3.605551275463989f, 3.872983346207417f};
    float p = 0.0f;
    #pragma unroll
    for (int n = 0; n < 8; n++) {
        float sn = s[n];
        float as = fmaf(R[n], p, (float)(n + 1) * sn);
        s[n] = fmaf(-inv_t, as, fmaf(xb, R[n], sn));
        p = fmaf(R[n], sn, p);
    }
}

// ---------------------------------------------------------------------------
// Kernel A: per-chunk runs; dumps sub-chunk boundary data every SUBL steps.
// ---------------------------------------------------------------------------
__global__ void hippo_chunk_kernel(const float* __restrict__ x_seq,
                                   float* __restrict__ Psub,  // [NCH][NSUB][8][8]
                                   float* __restrict__ Vsub,  // [NCH][NSUB][64][8]
                                   float* __restrict__ Pfin,  // [NCH][8][8]
                                   float* __restrict__ Vfin)  // [NCH][64][8]
{
    int chunk = blockIdx.x;
    int tid = threadIdx.x;
    if (tid >= 72) return;
    bool isP = tid >= 64;
    int col = tid - 64;
    int b = tid >> 1, c = tid & 1;

    float s[8];
    #pragma unroll
    for (int n = 0; n < 8; n++) s[n] = (isP && n == col) ? 1.0f : 0.0f;

    int t0 = chunk * CLEN;
    for (int i = 0; i < CLEN; i++) {
        if ((i & (SUBL - 1)) == 0) {
            int sub = i >> 3;
            if (isP) {
                #pragma unroll
                for (int n = 0; n < 8; n++)
                    Psub[(((size_t)chunk * NSUB + sub) * 8 + n) * 8 + col] = s[n];
            } else {
                #pragma unroll
                for (int n = 0; n < 8; n++)
                    Vsub[(((size_t)chunk * NSUB + sub) * 64 + tid) * 8 + n] = s[n];
            }
        }
        float tf = (float)(t0 + i + 1);
        float inv_t = 1.0f / tf;
        float x = 0.0f;
        if (!isP) x = x_seq[((size_t)(b * TLEN + t0 + i)) * 2 + c];
        hippo_step(s, inv_t, x * inv_t);
    }
    if (isP) {
        #pragma unroll
        for (int n = 0; n < 8; n++) Pfin[((size_t)chunk * 8 + n) * 8 + col] = s[n];
    } else {
        #pragma unroll
        for (int n = 0; n < 8; n++) Vfin[((size_t)chunk * 64 + tid) * 8 + n] = s[n];
    }
}

// ---------------------------------------------------------------------------
// Kernel B: sequential composition across chunks. One thread per (b,c).
// ---------------------------------------------------------------------------
__global__ void hippo_compose_kernel(const float* __restrict__ Pfin,
                                     const float* __restrict__ Vfin,
                                     float* __restrict__ S0)   // [NCH][64][8]
{
    int tid = threadIdx.x;   // 0..63
    float s[8];
    #pragma unroll
    for (int n = 0; n < 8; n++) s[n] = 0.0f;

    #pragma unroll 2
    for (int chunk = 0; chunk < NCH; chunk++) {
        #pragma unroll
        for (int n = 0; n < 8; n++) S0[((size_t)chunk * 64 + tid) * 8 + n] = s[n];
        float ns[8];
        #pragma unroll
        for (int n = 0; n < 8; n++) {
            float acc = Vfin[((size_t)chunk * 64 + tid) * 8 + n];
            #pragma unroll
            for (int m = 0; m < 8; m++)
                acc = fmaf(Pfin[((size_t)chunk * 8 + n) * 8 + m], s[m], acc);
            ns[n] = acc;
        }
        #pragma unroll
        for (int n = 0; n < 8; n++) s[n] = ns[n];
    }
}

// ---------------------------------------------------------------------------
// Kernel C: fine expand, plane-major output hT[16][NROWS].
// tid = sub | c<<3 | blo<<4 so a wave's 8 sub-lanes co-write each 64B line
// of a plane across their lockstep steps (L2 merges to full lines).
// ---------------------------------------------------------------------------
__global__ __launch_bounds__(256) void hippo_expand_kernel(
    const float* __restrict__ x_seq,
    const float* __restrict__ Psub,
    const float* __restrict__ Vsub,
    const float* __restrict__ S0,
    float* __restrict__ hT)              // [16][NROWS]
{
    int tid = threadIdx.x;
    int sub = tid & 7;
    int c = (tid >> 3) & 1;
    int blo = tid >> 4;                  // 0..15
    int chunk = blockIdx.x & 127;
    int bhi = blockIdx.x >> 7;           // 0..1
    int b = bhi * 16 + blo;
    int seq = b * 2 + c;

    float s0v[8];
    #pragma unroll
    for (int n = 0; n < 8; n++)
        s0v[n] = S0[((size_t)chunk * 64 + seq) * 8 + n];

    const float* Pp = &Psub[((size_t)chunk * NSUB + sub) * 64];
    const float* Vp = &Vsub[(((size_t)chunk * NSUB + sub) * 64 + seq) * 8];

    float s[8];
    #pragma unroll
    for (int n = 0; n < 8; n++) {
        float acc = Vp[n];
        #pragma unroll
        for (int m = 0; m < 8; m++)
            acc = fmaf(Pp[n * 8 + m], s0v[m], acc);
        s[n] = acc;
    }

    int t0 = chunk * CLEN + sub * SUBL;
    size_t rowbase = (size_t)b * TLEN;
    #pragma unroll
    for (int i = 0; i < SUBL; i++) {
        int t = t0 + i;
        float tf = (float)(t + 1);
        float inv_t = 1.0f / tf;
        float x = x_seq[(rowbase + t) * 2 + c];
        hippo_step(s, inv_t, x * inv_t);
        #pragma unroll
        for (int n = 0; n < 8; n++)
            hT[(size_t)(c * 8 + n) * NROWS + rowbase + t] = s[n];
    }
}

// ---------------------------------------------------------------------------
// KAN helpers
// ---------------------------------------------------------------------------
__device__ __forceinline__ void bspline4(float x, float& B0, float& B1,
                                         float& B2, float& B3, int& m)
{
    float tt = fmaf(x, 5.0f, 8.0f);        // (x + 1.6) * 5
    float fm = floorf(tt);
    float u = tt - fm;
    bool valid = (fm >= 0.0f) && (fm <= 15.0f);
    float u2 = u * u, u3 = u2 * u;
    float um = 1.0f - u;
    B0 = um * um * um * (1.0f / 6.0f);
    B3 = u3 * (1.0f / 6.0f);
    B1 = fmaf(3.0f, u3, fmaf(-6.0f, u2, 4.0f)) * (1.0f / 6.0f);
    B2 = fmaf(-3.0f, u3, fmaf(3.0f, u2, fmaf(3.0f, u, 1.0f))) * (1.0f / 6.0f);
    float msk = valid ? 1.0f : 0.0f;
    B0 *= msk; B1 *= msk; B2 *= msk; B3 *= msk;
    m = valid ? (int)fm : 0;
}

__device__ __forceinline__ float silu(float x) {
    return x / (1.0f + __expf(-x));
}

// Round-1 skeleton (rolled i-loops, VGPR ~52): layers 1/2 rolled with x
// prefetch rotation; layer 3 fully unrolled with acc2 in registers and
// ws3/wb3 from global (L1-hot, 832 B). LDS exactly 40960 B -> 4 blocks/CU.
__global__ __launch_bounds__(256) void kan_kernel(
    const float* __restrict__ hT,        // [16][NROWS]
    float* __restrict__ out1T,           // [32][NROWS]
    const float* __restrict__ wb1, const float* __restrict__ ws1,
    const float* __restrict__ wb2, const float* __restrict__ ws2,
    const float* __restrict__ wb3, const float* __restrict__ ws3,
    float* __restrict__ out)
{
    __shared__ float wlds[10240];        // phase1: ws1p[32][304]+wb1[512]
                                         // phase2: ws2p[16][608]+wb2[512]
    int tid = threadIdx.x;
    int row = blockIdx.x * 256 + tid;

    // ---- stage phase 1
    for (int idx = tid; idx < 10240; idx += 256) {
        float v;
        if (idx < 9728) {
            int o = idx / 304;
            int k = idx - o * 304;
            int ii = k / 19;
            int jj = k - ii * 19 - 3;
            v = (jj >= 0 && jj < 13) ? ws1[o * 208 + ii * 13 + jj] : 0.0f;
        } else {
            v = wb1[idx - 9728];
        }
        wlds[idx] = v;
    }
    __syncthreads();

    // ---- layer 1: 16 -> 32 (rolled, prefetch next x)
    float acc1[32];
    #pragma unroll
    for (int o = 0; o < 32; o++) acc1[o] = 0.0f;

    float xc = hT[row];
    #pragma unroll 1
    for (int i = 0; i < 16; i++) {
        float xn = hT[(size_t)((i + 1) & 15) * NROWS + row];
        float sx = silu(xc);
        float B0, B1, B2, B3; int m;
        bspline4(xc, B0, B1, B2, B3, m);
        const float* wp = &wlds[i * 19 + m];
        const float* wbp = &wlds[9728 + i];
        #pragma unroll
        for (int o = 0; o < 32; o++) {
            float a = acc1[o];
            a = fmaf(sx, wbp[o * 16], a);
            const float* w = wp + o * 304;
            a = fmaf(B0, w[0], a);
            a = fmaf(B1, w[1], a);
            a = fmaf(B2, w[2], a);
            a = fmaf(B3, w[3], a);
            acc1[o] = a;
        }
        xc = xn;
    }
    #pragma unroll
    for (int o = 0; o < 32; o++) out1T[(size_t)o * NROWS + row] = acc1[o];

    __syncthreads();   // all waves done reading phase-1 weights

    // ---- stage phase 2
    for (int idx = tid; idx < 10240; idx += 256) {
        float v;
        if (idx < 9728) {
            int o = idx / 608;
            int k = idx - o * 608;
            int ii = k / 19;
            int jj = k - ii * 19 - 3;
            v = (jj >= 0 && jj < 13) ? ws2[o * 416 + ii * 13 + jj] : 0.0f;
        } else {
            v = wb2[idx - 9728];
        }
        wlds[idx] = v;
    }
    __syncthreads();

    // ---- layer 2: 32 -> 16 (rolled, prefetch next x)
    float acc2[16];
    #pragma unroll
    for (int o = 0; o < 16; o++) acc2[o] = 0.0f;

    float yc = out1T[row];
    #pragma unroll 1
    for (int i = 0; i < 32; i++) {
        float yn = out1T[(size_t)((i + 1) & 31) * NROWS + row];
        float sx = silu(yc);
        float B0, B1, B2, B3; int m;
        bspline4(yc, B0, B1, B2, B3, m);
        const float* wp = &wlds[i * 19 + m];
        const float* wbp = &wlds[9728 + i];
        #pragma unroll
        for (int o = 0; o < 16; o++) {
            float a = acc2[o];
            a = fmaf(sx, wbp[o * 32], a);
            const float* w = wp + o * 608;
            a = fmaf(B0, w[0], a);
            a = fmaf(B1, w[1], a);
            a = fmaf(B2, w[2], a);
            a = fmaf(B3, w[3], a);
            acc2[o] = a;
        }
        yc = yn;
    }

    // ---- layer 3: 16 -> 1, fully unrolled, acc2 in regs, weights from global
    float acc3 = 0.0f;
    #pragma unroll
    for (int i = 0; i < 16; i++) {
        float xv = acc2[i];
        float sx = silu(xv);
        float B0, B1, B2, B3; int m;
        bspline4(xv, B0, B1, B2, B3, m);
        acc3 = fmaf(sx, wb3[i], acc3);
        const float* w3 = &ws3[i * 13];
        int j0 = m - 3;
        float w0 = (j0 >= 0)            ? w3[j0]     : 0.0f;
        float w1 = (j0 >= -1)           ? w3[j0 + 1] : 0.0f;
        float w2 = (j0 >= -2)           ? w3[j0 + 2] : 0.0f;
        float w3v = (j0 + 3 < 13)       ? w3[j0 + 3] : 0.0f;
        // j0 in [-3,12]: upper bound only binds for the last tap
        acc3 = fmaf(B0, w0, acc3);
        acc3 = fmaf(B1, w1, acc3);
        acc3 = fmaf(B2, w2, acc3);
        acc3 = fmaf(B3, w3v, acc3);
    }
    out[row] = acc3;
}

// ---------------------------------------------------------------------------
extern "C" void kernel_launch(void* const* d_in, const int* in_sizes, int n_in,
                              void* d_out, int out_size, void* d_ws, size_t ws_size,
                              hipStream_t stream) {
    const float* x_seq = (const float*)d_in[0];
    const float* wb1   = (const float*)d_in[1];
    const float* ws1   = (const float*)d_in[2];
    const float* wb2   = (const float*)d_in[3];
    const float* ws2   = (const float*)d_in[4];
    const float* wb3   = (const float*)d_in[5];
    const float* ws3   = (const float*)d_in[6];

    float* ws   = (float*)d_ws;
    float* Psub = ws;                   // 128*8*64        =   65536
    float* Vsub = ws + 65536;           // 128*8*64*8      =  524288
    float* Pfin = ws + 589824;          // 128*64          =    8192
    float* Vfin = ws + 598016;          // 128*64*8        =   65536
    float* S0   = ws + 663552;          // 128*64*8        =   65536
    float* hT   = ws + 729088;          // 16*262144       = 4194304
    float* out1T= ws + 4923392;         // 32*262144       = 8388608
    float* out  = (float*)d_out;

    hipLaunchKernelGGL(hippo_chunk_kernel,   dim3(NCH), dim3(128), 0, stream,
                       x_seq, Psub, Vsub, Pfin, Vfin);
    hipLaunchKernelGGL(hippo_compose_kernel, dim3(1),   dim3(64),  0, stream,
                       Pfin, Vfin, S0);
    hipLaunchKernelGGL(hippo_expand_kernel,  dim3(256), dim3(256), 0, stream,
                       x_seq, Psub, Vsub, S0, hT);
    hipLaunchKernelGGL(kan_kernel, dim3(NROWS / 256), dim3(256), 0, stream,
                       hT, out1T, wb1, ws1, wb2, ws2, wb3, ws3, out);
}

// Round 5
// 192.167 us; speedup vs baseline: 12.1370x; 1.1493x over previous
//
#include <hip/hip_runtime.h>
#include <math.h>

#define BATCH 32
#define TLEN 8192
#define NCH 64           // chunks
#define CLEN 128         // steps per chunk
#define SUBL 8           // steps per sub-chunk
#define NSUB 16          // sub-chunks per chunk
#define NROWS (BATCH*TLEN)   // 262144 rows

// ---------------------------------------------------------------------------
// HiPPO step: s <- (I - A/t) s + (x/t) * r
// ---------------------------------------------------------------------------
__device__ __forceinline__ void hippo_step(float s[8], float inv_t, float xb) {
    const float R[8] = {1.0f, 1.7320508075688772f, 2.23606797749979f,
                        2.6457513110645907f, 3.0f, 3.3166247903554f,
                        3.605551275463989f, 3.872983346207417f};
    float p = 0.0f;
    #pragma unroll
    for (int n = 0; n < 8; n++) {
        float sn = s[n];
        float as = fmaf(R[n], p, (float)(n + 1) * sn);
        s[n] = fmaf(-inv_t, as, fmaf(xb, R[n], sn));
        p = fmaf(R[n], sn, p);
    }
}

// ---------------------------------------------------------------------------
// Kernel A: per-chunk runs; dumps sub-chunk boundary data every SUBL steps.
// ---------------------------------------------------------------------------
__global__ void hippo_chunk_kernel(const float* __restrict__ x_seq,
                                   float* __restrict__ Psub,  // [NCH][NSUB][8][8]
                                   float* __restrict__ Vsub,  // [NCH][NSUB][64][8]
                                   float* __restrict__ Pfin,  // [NCH][8][8]
                                   float* __restrict__ Vfin)  // [NCH][64][8]
{
    int chunk = blockIdx.x;
    int tid = threadIdx.x;
    if (tid >= 72) return;
    bool isP = tid >= 64;
    int col = tid - 64;
    int b = tid >> 1, c = tid & 1;

    float s[8];
    #pragma unroll
    for (int n = 0; n < 8; n++) s[n] = (isP && n == col) ? 1.0f : 0.0f;

    int t0 = chunk * CLEN;
    for (int i = 0; i < CLEN; i++) {
        if ((i & (SUBL - 1)) == 0) {
            int sub = i >> 3;
            if (isP) {
                #pragma unroll
                for (int n = 0; n < 8; n++)
                    Psub[(((size_t)chunk * NSUB + sub) * 8 + n) * 8 + col] = s[n];
            } else {
                #pragma unroll
                for (int n = 0; n < 8; n++)
                    Vsub[(((size_t)chunk * NSUB + sub) * 64 + tid) * 8 + n] = s[n];
            }
        }
        float tf = (float)(t0 + i + 1);
        float inv_t = 1.0f / tf;
        float x = 0.0f;
        if (!isP) x = x_seq[((size_t)(b * TLEN + t0 + i)) * 2 + c];
        hippo_step(s, inv_t, x * inv_t);
    }
    if (isP) {
        #pragma unroll
        for (int n = 0; n < 8; n++) Pfin[((size_t)chunk * 8 + n) * 8 + col] = s[n];
    } else {
        #pragma unroll
        for (int n = 0; n < 8; n++) Vfin[((size_t)chunk * 64 + tid) * 8 + n] = s[n];
    }
}

// ---------------------------------------------------------------------------
// Kernel B: sequential composition across 64 chunks. One thread per (b,c).
// ---------------------------------------------------------------------------
__global__ void hippo_compose_kernel(const float* __restrict__ Pfin,
                                     const float* __restrict__ Vfin,
                                     float* __restrict__ S0)   // [NCH][64][8]
{
    int tid = threadIdx.x;   // 0..63
    float s[8];
    #pragma unroll
    for (int n = 0; n < 8; n++) s[n] = 0.0f;

    #pragma unroll 2
    for (int chunk = 0; chunk < NCH; chunk++) {
        #pragma unroll
        for (int n = 0; n < 8; n++) S0[((size_t)chunk * 64 + tid) * 8 + n] = s[n];
        float ns[8];
        #pragma unroll
        for (int n = 0; n < 8; n++) {
            float acc = Vfin[((size_t)chunk * 64 + tid) * 8 + n];
            #pragma unroll
            for (int m = 0; m < 8; m++)
                acc = fmaf(Pfin[((size_t)chunk * 8 + n) * 8 + m], s[m], acc);
            ns[n] = acc;
        }
        #pragma unroll
        for (int n = 0; n < 8; n++) s[n] = ns[n];
    }
}

// ---------------------------------------------------------------------------
// Kernel C: fine expand, plane-major output hT[16][NROWS].
// tid = sub | c<<4 | blo<<5 : 16 sub-lanes of one (b,c) cover 128 consecutive
// t -> a wave's stores land in 32 lines/instr.
// ---------------------------------------------------------------------------
__global__ __launch_bounds__(256) void hippo_expand_kernel(
    const float* __restrict__ x_seq,
    const float* __restrict__ Psub,
    const float* __restrict__ Vsub,
    const float* __restrict__ S0,
    float* __restrict__ hT)              // [16][NROWS]
{
    int tid = threadIdx.x;
    int sub = tid & 15;
    int c = (tid >> 4) & 1;
    int blo = tid >> 5;                  // 0..7
    int bhi = blockIdx.x & 3;            // 0..3
    int chunk = blockIdx.x >> 2;         // 0..63
    int b = bhi * 8 + blo;
    int seq = b * 2 + c;

    float s0v[8];
    #pragma unroll
    for (int n = 0; n < 8; n++)
        s0v[n] = S0[((size_t)chunk * 64 + seq) * 8 + n];

    const float* Pp = &Psub[((size_t)chunk * NSUB + sub) * 64];
    const float* Vp = &Vsub[(((size_t)chunk * NSUB + sub) * 64 + seq) * 8];

    float s[8];
    #pragma unroll
    for (int n = 0; n < 8; n++) {
        float acc = Vp[n];
        #pragma unroll
        for (int m = 0; m < 8; m++)
            acc = fmaf(Pp[n * 8 + m], s0v[m], acc);
        s[n] = acc;
    }

    int t0 = chunk * CLEN + sub * SUBL;
    size_t rowbase = (size_t)b * TLEN;
    #pragma unroll
    for (int i = 0; i < SUBL; i++) {
        int t = t0 + i;
        float tf = (float)(t + 1);
        float inv_t = 1.0f / tf;
        float x = x_seq[(rowbase + t) * 2 + c];
        hippo_step(s, inv_t, x * inv_t);
        #pragma unroll
        for (int n = 0; n < 8; n++)
            hT[(size_t)(c * 8 + n) * NROWS + rowbase + t] = s[n];
    }
}

// ---------------------------------------------------------------------------
// KAN helpers
// ---------------------------------------------------------------------------
__device__ __forceinline__ void bspline4(float x, float& B0, float& B1,
                                         float& B2, float& B3, int& m)
{
    float tt = fmaf(x, 5.0f, 8.0f);        // (x + 1.6) * 5
    float fm = floorf(tt);
    float u = tt - fm;
    bool valid = (fm >= 0.0f) && (fm <= 15.0f);
    float u2 = u * u, u3 = u2 * u;
    float um = 1.0f - u;
    B0 = um * um * um * (1.0f / 6.0f);
    B3 = u3 * (1.0f / 6.0f);
    B1 = fmaf(3.0f, u3, fmaf(-6.0f, u2, 4.0f)) * (1.0f / 6.0f);
    B2 = fmaf(-3.0f, u3, fmaf(3.0f, u2, fmaf(3.0f, u, 1.0f))) * (1.0f / 6.0f);
    float msk = valid ? 1.0f : 0.0f;
    B0 *= msk; B1 *= msk; B2 *= msk; B3 *= msk;
    m = valid ? (int)fm : 0;
}

__device__ __forceinline__ float silu(float x) {
    return x / (1.0f + __expf(-x));
}

// Rolled i-loops (VGPR-stable), 2-deep input prefetch, transposed base
// weights in LDS (wbT[i][o] -> b128-mergeable uniform reads).
// __launch_bounds__(256,2): plan regalloc for the grid's real occupancy
// (4 waves/SIMD) -> ~128 VGPR budget for deeper LDS pipelining.
__global__ __launch_bounds__(256, 2) void kan_kernel(
    const float* __restrict__ hT,        // [16][NROWS]
    float* __restrict__ out1T,           // [32][NROWS]
    const float* __restrict__ wb1, const float* __restrict__ ws1,
    const float* __restrict__ wb2, const float* __restrict__ ws2,
    const float* __restrict__ wb3, const float* __restrict__ ws3,
    float* __restrict__ out)
{
    __shared__ float wlds[10240];        // phase1: ws1p[32][304]+wbT1[16][32]
                                         // phase2: ws2p[16][608]+wbT2[32][16]
    int tid = threadIdx.x;
    int row = blockIdx.x * 256 + tid;

    // ---- stage phase 1
    for (int idx = tid; idx < 10240; idx += 256) {
        float v;
        if (idx < 9728) {
            int o = idx / 304;
            int k = idx - o * 304;
            int ii = k / 19;
            int jj = k - ii * 19 - 3;
            v = (jj >= 0 && jj < 13) ? ws1[o * 208 + ii * 13 + jj] : 0.0f;
        } else {
            int k = idx - 9728;
            int ii = k >> 5, oo = k & 31;
            v = wb1[oo * 16 + ii];
        }
        wlds[idx] = v;
    }
    __syncthreads();

    // ---- layer 1: 16 -> 32 (rolled, 2-deep prefetch)
    float acc1[32];
    #pragma unroll
    for (int o = 0; o < 32; o++) acc1[o] = 0.0f;

    float xc = hT[row];
    float xn = hT[(size_t)NROWS + row];
    #pragma unroll 1
    for (int i = 0; i < 16; i++) {
        float xf = hT[(size_t)((i + 2) & 15) * NROWS + row];
        float sx = silu(xc);
        float B0, B1, B2, B3; int m;
        bspline4(xc, B0, B1, B2, B3, m);
        const float* wp = &wlds[i * 19 + m];
        const float* wbp = &wlds[9728 + i * 32];
        #pragma unroll
        for (int o = 0; o < 32; o++) {
            float a = acc1[o];
            a = fmaf(sx, wbp[o], a);
            const float* w = wp + o * 304;
            a = fmaf(B0, w[0], a);
            a = fmaf(B1, w[1], a);
            a = fmaf(B2, w[2], a);
            a = fmaf(B3, w[3], a);
            acc1[o] = a;
        }
        xc = xn; xn = xf;
    }
    #pragma unroll
    for (int o = 0; o < 32; o++) out1T[(size_t)o * NROWS + row] = acc1[o];

    __syncthreads();   // all waves done reading phase-1 weights

    // ---- stage phase 2
    for (int idx = tid; idx < 10240; idx += 256) {
        float v;
        if (idx < 9728) {
            int o = idx / 608;
            int k = idx - o * 608;
            int ii = k / 19;
            int jj = k - ii * 19 - 3;
            v = (jj >= 0 && jj < 13) ? ws2[o * 416 + ii * 13 + jj] : 0.0f;
        } else {
            int k = idx - 9728;
            int ii = k >> 4, oo = k & 15;
            v = wb2[oo * 32 + ii];
        }
        wlds[idx] = v;
    }
    __syncthreads();

    // ---- layer 2: 32 -> 16 (rolled, 2-deep prefetch)
    float acc2[16];
    #pragma unroll
    for (int o = 0; o < 16; o++) acc2[o] = 0.0f;

    float yc = out1T[row];
    float yn = out1T[(size_t)NROWS + row];
    #pragma unroll 1
    for (int i = 0; i < 32; i++) {
        float yf = out1T[(size_t)((i + 2) & 31) * NROWS + row];
        float sx = silu(yc);
        float B0, B1, B2, B3; int m;
        bspline4(yc, B0, B1, B2, B3, m);
        const float* wp = &wlds[i * 19 + m];
        const float* wbp = &wlds[9728 + i * 16];
        #pragma unroll
        for (int o = 0; o < 16; o++) {
            float a = acc2[o];
            a = fmaf(sx, wbp[o], a);
            const float* w = wp + o * 608;
            a = fmaf(B0, w[0], a);
            a = fmaf(B1, w[1], a);
            a = fmaf(B2, w[2], a);
            a = fmaf(B3, w[3], a);
            acc2[o] = a;
        }
        yc = yn; yn = yf;
    }

    // ---- layer 3: 16 -> 1, fully unrolled, acc2 in regs, weights from
    // global with BOTH-side guards (valid tap indices are 0..12).
    float acc3 = 0.0f;
    #pragma unroll
    for (int i = 0; i < 16; i++) {
        float xv = acc2[i];
        float sx = silu(xv);
        float B0, B1, B2, B3; int m;
        bspline4(xv, B0, B1, B2, B3, m);
        acc3 = fmaf(sx, wb3[i], acc3);
        const float* w3 = &ws3[i * 13];
        int j0 = m - 3;
        float w0v = (j0 >= 0)              ? w3[j0]     : 0.0f;
        float w1v = (j0 >= -1 && j0 <= 11) ? w3[j0 + 1] : 0.0f;
        float w2v = (j0 >= -2 && j0 <= 10) ? w3[j0 + 2] : 0.0f;
        float w3v = (j0 <= 9)              ? w3[j0 + 3] : 0.0f;
        acc3 = fmaf(B0, w0v, acc3);
        acc3 = fmaf(B1, w1v, acc3);
        acc3 = fmaf(B2, w2v, acc3);
        acc3 = fmaf(B3, w3v, acc3);
    }
    out[row] = acc3;
}

// ---------------------------------------------------------------------------
extern "C" void kernel_launch(void* const* d_in, const int* in_sizes, int n_in,
                              void* d_out, int out_size, void* d_ws, size_t ws_size,
                              hipStream_t stream) {
    const float* x_seq = (const float*)d_in[0];
    const float* wb1   = (const float*)d_in[1];
    const float* ws1   = (const float*)d_in[2];
    const float* wb2   = (const float*)d_in[3];
    const float* ws2   = (const float*)d_in[4];
    const float* wb3   = (const float*)d_in[5];
    const float* ws3   = (const float*)d_in[6];

    float* ws   = (float*)d_ws;
    float* Psub = ws;                   // 64*16*64        =   65536
    float* Vsub = ws + 65536;           // 64*16*64*8      =  524288
    float* Pfin = ws + 589824;          // 64*64           =    4096
    float* Vfin = ws + 593920;          // 64*64*8         =   32768
    float* S0   = ws + 626688;          // 64*64*8         =   32768
    float* hT   = ws + 659456;          // 16*262144       = 4194304
    float* out1T= ws + 4853760;         // 32*262144       = 8388608
    float* out  = (float*)d_out;

    hipLaunchKernelGGL(hippo_chunk_kernel,   dim3(NCH), dim3(128), 0, stream,
                       x_seq, Psub, Vsub, Pfin, Vfin);
    hipLaunchKernelGGL(hippo_compose_kernel, dim3(1),   dim3(64),  0, stream,
                       Pfin, Vfin, S0);
    hipLaunchKernelGGL(hippo_expand_kernel,  dim3(NCH * 4), dim3(256), 0, stream,
                       x_seq, Psub, Vsub, S0, hT);
    hipLaunchKernelGGL(kan_kernel, dim3(NROWS / 256), dim3(256), 0, stream,
                       hT, out1T, wb1, ws1, wb2, ws2, wb3, ws3, out);
}

// Round 6
// 178.565 us; speedup vs baseline: 13.0615x; 1.0762x over previous
//
#include <hip/hip_runtime.h>
#include <math.h>

#define BATCH 32
#define TLEN 8192
#define NCH 64           // chunks
#define CLEN 128         // steps per chunk
#define SUBL 8           // steps per sub-chunk
#define NSUB 16          // sub-chunks per chunk
#define NROWS (BATCH*TLEN)   // 262144 rows

typedef _Float16 h2 __attribute__((ext_vector_type(2)));
union HU { unsigned int u; h2 h; };
__device__ __forceinline__ h2 u2h(unsigned int x) { HU t; t.u = x; return t.h; }
__device__ __forceinline__ unsigned int pkh(float a, float b) {
    HU t; t.h = h2{(_Float16)a, (_Float16)b}; return t.u;
}

#if __has_builtin(__builtin_amdgcn_fdot2)
__device__ __forceinline__ float dot2f(h2 a, h2 b, float c) {
    return __builtin_amdgcn_fdot2(a, b, c, false);
}
#else
__device__ __forceinline__ float dot2f(h2 a, h2 b, float c) {
    // v_fma_mix pattern: f16 operands widened inside fp32 fma
    return fmaf((float)a.x, (float)b.x, fmaf((float)a.y, (float)b.y, c));
}
#endif

// ---------------------------------------------------------------------------
// HiPPO step: s <- (I - A/t) s + (x/t) * r
// ---------------------------------------------------------------------------
__device__ __forceinline__ void hippo_step(float s[8], float inv_t, float xb) {
    const float R[8] = {1.0f, 1.7320508075688772f, 2.23606797749979f,
                        2.6457513110645907f, 3.0f, 3.3166247903554f,
                        3.605551275463989f, 3.872983346207417f};
    float p = 0.0f;
    #pragma unroll
    for (int n = 0; n < 8; n++) {
        float sn = s[n];
        float as = fmaf(R[n], p, (float)(n + 1) * sn);
        s[n] = fmaf(-inv_t, as, fmaf(xb, R[n], sn));
        p = fmaf(R[n], sn, p);
    }
}

// ---------------------------------------------------------------------------
// Kernel A: per-chunk runs; dumps sub-chunk boundary data every SUBL steps.
// ---------------------------------------------------------------------------
__global__ void hippo_chunk_kernel(const float* __restrict__ x_seq,
                                   float* __restrict__ Psub,  // [NCH][NSUB][8][8]
                                   float* __restrict__ Vsub,  // [NCH][NSUB][64][8]
                                   float* __restrict__ Pfin,  // [NCH][8][8]
                                   float* __restrict__ Vfin)  // [NCH][64][8]
{
    int chunk = blockIdx.x;
    int tid = threadIdx.x;
    if (tid >= 72) return;
    bool isP = tid >= 64;
    int col = tid - 64;
    int b = tid >> 1, c = tid & 1;

    float s[8];
    #pragma unroll
    for (int n = 0; n < 8; n++) s[n] = (isP && n == col) ? 1.0f : 0.0f;

    int t0 = chunk * CLEN;
    for (int i = 0; i < CLEN; i++) {
        if ((i & (SUBL - 1)) == 0) {
            int sub = i >> 3;
            if (isP) {
                #pragma unroll
                for (int n = 0; n < 8; n++)
                    Psub[(((size_t)chunk * NSUB + sub) * 8 + n) * 8 + col] = s[n];
            } else {
                #pragma unroll
                for (int n = 0; n < 8; n++)
                    Vsub[(((size_t)chunk * NSUB + sub) * 64 + tid) * 8 + n] = s[n];
            }
        }
        float tf = (float)(t0 + i + 1);
        float inv_t = 1.0f / tf;
        float x = 0.0f;
        if (!isP) x = x_seq[((size_t)(b * TLEN + t0 + i)) * 2 + c];
        hippo_step(s, inv_t, x * inv_t);
    }
    if (isP) {
        #pragma unroll
        for (int n = 0; n < 8; n++) Pfin[((size_t)chunk * 8 + n) * 8 + col] = s[n];
    } else {
        #pragma unroll
        for (int n = 0; n < 8; n++) Vfin[((size_t)chunk * 64 + tid) * 8 + n] = s[n];
    }
}

// ---------------------------------------------------------------------------
// Kernel B: sequential composition across 64 chunks. One thread per (b,c).
// ---------------------------------------------------------------------------
__global__ void hippo_compose_kernel(const float* __restrict__ Pfin,
                                     const float* __restrict__ Vfin,
                                     float* __restrict__ S0)   // [NCH][64][8]
{
    int tid = threadIdx.x;   // 0..63
    float s[8];
    #pragma unroll
    for (int n = 0; n < 8; n++) s[n] = 0.0f;

    #pragma unroll 2
    for (int chunk = 0; chunk < NCH; chunk++) {
        #pragma unroll
        for (int n = 0; n < 8; n++) S0[((size_t)chunk * 64 + tid) * 8 + n] = s[n];
        float ns[8];
        #pragma unroll
        for (int n = 0; n < 8; n++) {
            float acc = Vfin[((size_t)chunk * 64 + tid) * 8 + n];
            #pragma unroll
            for (int m = 0; m < 8; m++)
                acc = fmaf(Pfin[((size_t)chunk * 8 + n) * 8 + m], s[m], acc);
            ns[n] = acc;
        }
        #pragma unroll
        for (int n = 0; n < 8; n++) s[n] = ns[n];
    }
}

// ---------------------------------------------------------------------------
// Kernel C: fine expand, plane-major output hT[16][NROWS].
// ---------------------------------------------------------------------------
__global__ __launch_bounds__(256) void hippo_expand_kernel(
    const float* __restrict__ x_seq,
    const float* __restrict__ Psub,
    const float* __restrict__ Vsub,
    const float* __restrict__ S0,
    float* __restrict__ hT)              // [16][NROWS]
{
    int tid = threadIdx.x;
    int sub = tid & 15;
    int c = (tid >> 4) & 1;
    int blo = tid >> 5;                  // 0..7
    int bhi = blockIdx.x & 3;            // 0..3
    int chunk = blockIdx.x >> 2;         // 0..63
    int b = bhi * 8 + blo;
    int seq = b * 2 + c;

    float s0v[8];
    #pragma unroll
    for (int n = 0; n < 8; n++)
        s0v[n] = S0[((size_t)chunk * 64 + seq) * 8 + n];

    const float* Pp = &Psub[((size_t)chunk * NSUB + sub) * 64];
    const float* Vp = &Vsub[(((size_t)chunk * NSUB + sub) * 64 + seq) * 8];

    float s[8];
    #pragma unroll
    for (int n = 0; n < 8; n++) {
        float acc = Vp[n];
        #pragma unroll
        for (int m = 0; m < 8; m++)
            acc = fmaf(Pp[n * 8 + m], s0v[m], acc);
        s[n] = acc;
    }

    int t0 = chunk * CLEN + sub * SUBL;
    size_t rowbase = (size_t)b * TLEN;
    #pragma unroll
    for (int i = 0; i < SUBL; i++) {
        int t = t0 + i;
        float tf = (float)(t + 1);
        float inv_t = 1.0f / tf;
        float x = x_seq[(rowbase + t) * 2 + c];
        hippo_step(s, inv_t, x * inv_t);
        #pragma unroll
        for (int n = 0; n < 8; n++)
            hT[(size_t)(c * 8 + n) * NROWS + rowbase + t] = s[n];
    }
}

// ---------------------------------------------------------------------------
// KAN helpers
// ---------------------------------------------------------------------------
__device__ __forceinline__ void bspline4(float x, float& B0, float& B1,
                                         float& B2, float& B3, int& m)
{
    float tt = fmaf(x, 5.0f, 8.0f);        // (x + 1.6) * 5
    float fm = floorf(tt);
    float u = tt - fm;
    bool valid = (fm >= 0.0f) && (fm <= 15.0f);
    float u2 = u * u, u3 = u2 * u;
    float um = 1.0f - u;
    B0 = um * um * um * (1.0f / 6.0f);
    B3 = u3 * (1.0f / 6.0f);
    B1 = fmaf(3.0f, u3, fmaf(-6.0f, u2, 4.0f)) * (1.0f / 6.0f);
    B2 = fmaf(-3.0f, u3, fmaf(3.0f, u2, fmaf(3.0f, u, 1.0f))) * (1.0f / 6.0f);
    float msk = valid ? 1.0f : 0.0f;
    B0 *= msk; B1 *= msk; B2 *= msk; B3 *= msk;
    m = valid ? (int)fm : 0;
}

__device__ __forceinline__ float silu(float x) {
    return x / (1.0f + __expf(-x));
}

// Spline weights in LDS as f16 pairs, dual-alignment copies per (i,o) row of
// 19 dwords: copyE (pairs from even padded idx) at p=0..9, copyO (odd) at
// p=10..18. For interval m the 4 taps are dwords {poff, poff+1} where
// poff = m even ? m/2 : 10+(m-1)/2  -> one ds_read2_b32 + two v_dot2.
__global__ __launch_bounds__(256, 2) void kan_kernel(
    const float* __restrict__ hT,        // [16][NROWS]
    float* __restrict__ out1T,           // [32][NROWS]
    const float* __restrict__ wb1, const float* __restrict__ ws1,
    const float* __restrict__ wb2, const float* __restrict__ ws2,
    const float* __restrict__ wb3, const float* __restrict__ ws3,
    float* __restrict__ out)
{
    // phase1: W1 f16-pairs [i<16][o<32][19] @0..9728, wbT1 f32 @9728..10240
    // phase2: W2 f16-pairs [i<32][o<16][19] @0..9728, wbT2 f32 @9728..10240
    __shared__ unsigned int wldsU[10240];   // 40960 B -> 3 blocks/CU
    int tid = threadIdx.x;
    int row = blockIdx.x * 256 + tid;

    // ---- stage phase 1
    for (int idx = tid; idx < 10240; idx += 256) {
        unsigned int v;
        if (idx < 9728) {
            int i = idx / 608;
            int r = idx - i * 608;
            int o = r / 19;
            int p = r - o * 19;
            int j0 = (p < 10) ? (2 * p) : (2 * (p - 10) + 1);
            int j1 = j0 + 1;
            float lo = (j0 >= 3 && j0 <= 15) ? ws1[o * 208 + i * 13 + (j0 - 3)] : 0.0f;
            float hi = (j1 >= 3 && j1 <= 15) ? ws1[o * 208 + i * 13 + (j1 - 3)] : 0.0f;
            v = pkh(lo, hi);
        } else {
            int k = idx - 9728;
            int i = k >> 5, o = k & 31;
            v = __float_as_uint(wb1[o * 16 + i]);
        }
        wldsU[idx] = v;
    }
    __syncthreads();

    // ---- layer 1: 16 -> 32 (rolled, 2-deep prefetch)
    float acc1[32];
    #pragma unroll
    for (int o = 0; o < 32; o++) acc1[o] = 0.0f;

    float xc = hT[row];
    float xn = hT[(size_t)NROWS + row];
    #pragma unroll 1
    for (int i = 0; i < 16; i++) {
        float xf = hT[(size_t)((i + 2) & 15) * NROWS + row];
        float sx = silu(xc);
        float B0, B1, B2, B3; int m;
        bspline4(xc, B0, B1, B2, B3, m);
        h2 B01 = u2h(pkh(B0, B1));
        h2 B23 = u2h(pkh(B2, B3));
        int poff = (m & 1) ? (10 + ((m - 1) >> 1)) : (m >> 1);
        int base = i * 608 + poff;
        int wbb = 9728 + i * 32;
        #pragma unroll
        for (int o = 0; o < 32; o++) {
            unsigned int da = wldsU[base + o * 19];
            unsigned int db = wldsU[base + o * 19 + 1];
            float a = acc1[o];
            a = dot2f(B01, u2h(da), a);
            a = dot2f(B23, u2h(db), a);
            a = fmaf(sx, __uint_as_float(wldsU[wbb + o]), a);
            acc1[o] = a;
        }
        xc = xn; xn = xf;
    }
    #pragma unroll
    for (int o = 0; o < 32; o++) out1T[(size_t)o * NROWS + row] = acc1[o];

    __syncthreads();   // all waves done reading phase-1 weights

    // ---- stage phase 2
    for (int idx = tid; idx < 10240; idx += 256) {
        unsigned int v;
        if (idx < 9728) {
            int i = idx / 304;
            int r = idx - i * 304;
            int o = r / 19;
            int p = r - o * 19;
            int j0 = (p < 10) ? (2 * p) : (2 * (p - 10) + 1);
            int j1 = j0 + 1;
            float lo = (j0 >= 3 && j0 <= 15) ? ws2[o * 416 + i * 13 + (j0 - 3)] : 0.0f;
            float hi = (j1 >= 3 && j1 <= 15) ? ws2[o * 416 + i * 13 + (j1 - 3)] : 0.0f;
            v = pkh(lo, hi);
        } else {
            int k = idx - 9728;
            int i = k >> 4, o = k & 15;
            v = __float_as_uint(wb2[o * 32 + i]);
        }
        wldsU[idx] = v;
    }
    __syncthreads();

    // ---- layer 2: 32 -> 16 (rolled, 2-deep prefetch)
    float acc2[16];
    #pragma unroll
    for (int o = 0; o < 16; o++) acc2[o] = 0.0f;

    float yc = out1T[row];
    float yn = out1T[(size_t)NROWS + row];
    #pragma unroll 1
    for (int i = 0; i < 32; i++) {
        float yf = out1T[(size_t)((i + 2) & 31) * NROWS + row];
        float sx = silu(yc);
        float B0, B1, B2, B3; int m;
        bspline4(yc, B0, B1, B2, B3, m);
        h2 B01 = u2h(pkh(B0, B1));
        h2 B23 = u2h(pkh(B2, B3));
        int poff = (m & 1) ? (10 + ((m - 1) >> 1)) : (m >> 1);
        int base = i * 304 + poff;
        int wbb = 9728 + i * 16;
        #pragma unroll
        for (int o = 0; o < 16; o++) {
            unsigned int da = wldsU[base + o * 19];
            unsigned int db = wldsU[base + o * 19 + 1];
            float a = acc2[o];
            a = dot2f(B01, u2h(da), a);
            a = dot2f(B23, u2h(db), a);
            a = fmaf(sx, __uint_as_float(wldsU[wbb + o]), a);
            acc2[o] = a;
        }
        yc = yn; yn = yf;
    }

    // ---- layer 3: 16 -> 1, fully unrolled, acc2 in regs, fp32 weights from
    // global with both-side guards (valid tap indices 0..12).
    float acc3 = 0.0f;
    #pragma unroll
    for (int i = 0; i < 16; i++) {
        float xv = acc2[i];
        float sx = silu(xv);
        float B0, B1, B2, B3; int m;
        bspline4(xv, B0, B1, B2, B3, m);
        acc3 = fmaf(sx, wb3[i], acc3);
        const float* w3 = &ws3[i * 13];
        int j0 = m - 3;
        float w0v = (j0 >= 0)              ? w3[j0]     : 0.0f;
        float w1v = (j0 >= -1 && j0 <= 11) ? w3[j0 + 1] : 0.0f;
        float w2v = (j0 >= -2 && j0 <= 10) ? w3[j0 + 2] : 0.0f;
        float w3v = (j0 <= 9)              ? w3[j0 + 3] : 0.0f;
        acc3 = fmaf(B0, w0v, acc3);
        acc3 = fmaf(B1, w1v, acc3);
        acc3 = fmaf(B2, w2v, acc3);
        acc3 = fmaf(B3, w3v, acc3);
    }
    out[row] = acc3;
}

// ---------------------------------------------------------------------------
extern "C" void kernel_launch(void* const* d_in, const int* in_sizes, int n_in,
                              void* d_out, int out_size, void* d_ws, size_t ws_size,
                              hipStream_t stream) {
    const float* x_seq = (const float*)d_in[0];
    const float* wb1   = (const float*)d_in[1];
    const float* ws1   = (const float*)d_in[2];
    const float* wb2   = (const float*)d_in[3];
    const float* ws2   = (const float*)d_in[4];
    const float* wb3   = (const float*)d_in[5];
    const float* ws3   = (const float*)d_in[6];

    float* ws   = (float*)d_ws;
    float* Psub = ws;                   // 64*16*64        =   65536
    float* Vsub = ws + 65536;           // 64*16*64*8      =  524288
    float* Pfin = ws + 589824;          // 64*64           =    4096
    float* Vfin = ws + 593920;          // 64*64*8         =   32768
    float* S0   = ws + 626688;          // 64*64*8         =   32768
    float* hT   = ws + 659456;          // 16*262144       = 4194304
    float* out1T= ws + 4853760;         // 32*262144       = 8388608
    float* out  = (float*)d_out;

    hipLaunchKernelGGL(hippo_chunk_kernel,   dim3(NCH), dim3(128), 0, stream,
                       x_seq, Psub, Vsub, Pfin, Vfin);
    hipLaunchKernelGGL(hippo_compose_kernel, dim3(1),   dim3(64),  0, stream,
                       Pfin, Vfin, S0);
    hipLaunchKernelGGL(hippo_expand_kernel,  dim3(NCH * 4), dim3(256), 0, stream,
                       x_seq, Psub, Vsub, S0, hT);
    hipLaunchKernelGGL(kan_kernel, dim3(NROWS / 256), dim3(256), 0, stream,
                       hT, out1T, wb1, ws1, wb2, ws2, wb3, ws3, out);
}